// Round 1
// baseline (137.101 us; speedup 1.0000x reference)
//
#include <hip/hip_runtime.h>

#define L 256
#define DH 512
#define BQ 2
#define CCLIP 5.0f
#define TI 2

// ---------- shared 64x64x16 fp32 GEMM tile accumulator (256 thr, 4x4 micro) ----------
__device__ __forceinline__ void gemm64_acc(const float* __restrict__ A,
                                           const float* __restrict__ Bm,
                                           int K, int N, int m0, int n0,
                                           float (&acc)[4][4],
                                           float (*As)[68], float (*Bs)[68])
{
  const int tid  = threadIdx.x;
  const int tx   = tid & 15, ty = tid >> 4;
  const int arow = tid >> 2;          // 0..63
  const int akg  = (tid & 3) << 2;    // 0,4,8,12
  const int brow = tid >> 4;          // 0..15
  const int bng  = (tid & 15) << 2;   // 0..60

  for (int kt = 0; kt < K; kt += 16) {
    const float4 av = *(const float4*)(A  + (size_t)(m0 + arow) * K + kt + akg);
    const float4 bv = *(const float4*)(Bm + (size_t)(kt + brow) * N + n0 + bng);
    __syncthreads();
    As[akg + 0][arow] = av.x;
    As[akg + 1][arow] = av.y;
    As[akg + 2][arow] = av.z;
    As[akg + 3][arow] = av.w;
    *(float4*)(&Bs[brow][bng]) = bv;
    __syncthreads();
#pragma unroll
    for (int kk = 0; kk < 16; ++kk) {
      const float4 a = *(const float4*)(&As[kk][ty << 2]);
      const float4 b = *(const float4*)(&Bs[kk][tx << 2]);
      const float ap[4] = {a.x, a.y, a.z, a.w};
      const float bp[4] = {b.x, b.y, b.z, b.w};
#pragma unroll
      for (int p = 0; p < 4; ++p)
#pragma unroll
        for (int q = 0; q < 4; ++q)
          acc[p][q] = fmaf(ap[p], bp[q], acc[p][q]);
    }
  }
}

// ---------- kernel 1: rep = elu(x @ fc_w + fc_b) ----------
__global__ __launch_bounds__(256) void k_rep(const float* __restrict__ x,
    const float* __restrict__ fc_w, const float* __restrict__ fc_b,
    float* __restrict__ rep)
{
  __shared__ float As[16][68], Bs[16][68];
  float acc[4][4] = {};
  const int m0 = blockIdx.y * 64, n0 = blockIdx.x * 64;
  gemm64_acc(x, fc_w, DH, DH, m0, n0, acc, As, Bs);
  const int tx = threadIdx.x & 15, ty = threadIdx.x >> 4;
#pragma unroll
  for (int p = 0; p < 4; ++p) {
    const int m = m0 + (ty << 2) + p;
#pragma unroll
    for (int q = 0; q < 4; ++q) {
      const int n = n0 + (tx << 2) + q;
      const float v = acc[p][q] + fc_b[n];
      rep[(size_t)m * DH + n] = v > 0.0f ? v : (__expf(v) - 1.0f);
    }
  }
}

// ---------- kernel 2: dep = rep@w1+b1 ; head = rep@w2+b2 ; g1 = rep@wf1 ----------
__global__ __launch_bounds__(256) void k_triple(const float* __restrict__ rep,
    const float* __restrict__ w1, const float* __restrict__ b1,
    const float* __restrict__ w2, const float* __restrict__ b2,
    const float* __restrict__ wf1,
    float* __restrict__ dep, float* __restrict__ head, float* __restrict__ g1)
{
  __shared__ float As[16][68], Bs[16][68];
  const float* Bm; const float* bias; float* outp;
  if      (blockIdx.z == 0) { Bm = w1;  bias = b1;      outp = dep;  }
  else if (blockIdx.z == 1) { Bm = w2;  bias = b2;      outp = head; }
  else                      { Bm = wf1; bias = nullptr; outp = g1;   }
  float acc[4][4] = {};
  const int m0 = blockIdx.y * 64, n0 = blockIdx.x * 64;
  gemm64_acc(rep, Bm, DH, DH, m0, n0, acc, As, Bs);
  const int tx = threadIdx.x & 15, ty = threadIdx.x >> 4;
#pragma unroll
  for (int p = 0; p < 4; ++p) {
    const int m = m0 + (ty << 2) + p;
#pragma unroll
    for (int q = 0; q < 4; ++q) {
      const int n = n0 + (tx << 2) + q;
      float v = acc[p][q];
      if (bias) v += bias[n];
      outp[(size_t)m * DH + n] = v;
    }
  }
}

// ---------- kernel 3: masked tanh-clip softmax attention ----------
// attn_out[b,i,h] = sum_{j allowed} softmax_j( C*tanh((dep[b,j,h]+head[b,i,h]+bl[h])/C) ) * rep[b,j,h]
// fw mask: allowed j>i ; row i=L-1 fully masked -> uniform 1/L weights (fp32 rounding of -1e9+t).
__global__ __launch_bounds__(512) void k_attn(const float* __restrict__ dep,
    const float* __restrict__ head, const float* __restrict__ rep,
    const float* __restrict__ b_logit, float* __restrict__ attn_out)
{
  const int h  = threadIdx.x;
  const int b  = blockIdx.y;
  const int i0 = blockIdx.x * TI;
  const float* depb = dep + (size_t)b * L * DH;
  const float* repb = rep + (size_t)b * L * DH;
  const float invs = 2.0f / CCLIP;
  const float twoC = 2.0f * CCLIP;

  float hb[TI], sa[TI], aa[TI];
#pragma unroll
  for (int r = 0; r < TI; ++r) {
    hb[r] = head[((size_t)b * L + i0 + r) * DH + h] + b_logit[h];
    sa[r] = 0.0f; aa[r] = 0.0f;
  }
  const int jstart = (i0 + TI >= L) ? 0 : (i0 + 1);
  for (int j = jstart; j < L; ++j) {
    const float d  = depb[(size_t)j * DH + h];
    const float rv = repb[(size_t)j * DH + h];
#pragma unroll
    for (int r = 0; r < TI; ++r) {
      const int i = i0 + r;
      const float u = (d + hb[r]) * invs;            // 2*(dep+head+bl)/C
      const float e = __expf(u);
      const float t = CCLIP - twoC * __builtin_amdgcn_rcpf(e + 1.0f); // C*tanh(./C)
      float w = (j > i) ? __expf(t) : 0.0f;
      if (i == L - 1) w = 1.0f;                      // fully-masked row -> uniform
      sa[r] += w;
      aa[r] = fmaf(w, rv, aa[r]);
    }
  }
#pragma unroll
  for (int r = 0; r < TI; ++r)
    attn_out[((size_t)b * L + i0 + r) * DH + h] = aa[r] * __builtin_amdgcn_rcpf(sa[r]);
}

// ---------- kernel 4: g2 = attn@wf2 ; gate = sigmoid(g1+g2+bf) ; out = gate*rep+(1-gate)*attn ----------
__global__ __launch_bounds__(256) void k_final(const float* __restrict__ attn,
    const float* __restrict__ wf2, const float* __restrict__ g1,
    const float* __restrict__ rep, const float* __restrict__ bf,
    float* __restrict__ out)
{
  __shared__ float As[16][68], Bs[16][68];
  float acc[4][4] = {};
  const int m0 = blockIdx.y * 64, n0 = blockIdx.x * 64;
  gemm64_acc(attn, wf2, DH, DH, m0, n0, acc, As, Bs);
  const int tx = threadIdx.x & 15, ty = threadIdx.x >> 4;
#pragma unroll
  for (int p = 0; p < 4; ++p) {
    const int m = m0 + (ty << 2) + p;
#pragma unroll
    for (int q = 0; q < 4; ++q) {
      const int n = n0 + (tx << 2) + q;
      const size_t idx = (size_t)m * DH + n;
      const float s = g1[idx] + acc[p][q] + bf[n];
      const float gate = __builtin_amdgcn_rcpf(1.0f + __expf(-s));
      out[idx] = gate * rep[idx] + (1.0f - gate) * attn[idx];
    }
  }
}

extern "C" void kernel_launch(void* const* d_in, const int* in_sizes, int n_in,
                              void* d_out, int out_size, void* d_ws, size_t ws_size,
                              hipStream_t stream)
{
  const float* x       = (const float*)d_in[0];
  const float* fc_w    = (const float*)d_in[1];
  const float* fc_b    = (const float*)d_in[2];
  const float* w1_w    = (const float*)d_in[3];
  const float* w1_b    = (const float*)d_in[4];
  const float* w2_w    = (const float*)d_in[5];
  const float* w2_b    = (const float*)d_in[6];
  const float* b_logit = (const float*)d_in[7];
  const float* wf1_w   = (const float*)d_in[8];
  const float* wf2_w   = (const float*)d_in[9];
  const float* bf      = (const float*)d_in[10];
  float* out = (float*)d_out;

  float* ws   = (float*)d_ws;
  float* rep  = ws;
  float* dep  = ws + 1 * 262144;
  float* head = ws + 2 * 262144;
  float* g1   = ws + 3 * 262144;
  float* attn = ws + 4 * 262144;

  const dim3 blk(256);
  k_rep   <<<dim3(8, 8),    blk,       0, stream>>>(x, fc_w, fc_b, rep);
  k_triple<<<dim3(8, 8, 3), blk,       0, stream>>>(rep, w1_w, w1_b, w2_w, w2_b, wf1_w, dep, head, g1);
  k_attn  <<<dim3(L / TI, BQ), dim3(512), 0, stream>>>(dep, head, rep, b_logit, attn);
  k_final <<<dim3(8, 8),    blk,       0, stream>>>(attn, wf2_w, g1, rep, bf, out);
}

// Round 2
// 128.280 us; speedup vs baseline: 1.0688x; 1.0688x over previous
//
#include <hip/hip_runtime.h>

#define L 256
#define DH 512
#define BQ 2
#define CCLIP 5.0f
#define NC 4            // j-chunks for two-phase softmax
#define CH (L / NC)     // 64 j per chunk
#define TI2 2           // rows per phase-1 block

// ---------- shared 64x64x16 fp32 GEMM tile accumulator (256 thr, 4x4 micro) ----------
__device__ __forceinline__ void gemm64_acc(const float* __restrict__ A,
                                           const float* __restrict__ Bm,
                                           int K, int N, int m0, int n0,
                                           float (&acc)[4][4],
                                           float (*As)[68], float (*Bs)[68])
{
  const int tid  = threadIdx.x;
  const int tx   = tid & 15, ty = tid >> 4;
  const int arow = tid >> 2;          // 0..63
  const int akg  = (tid & 3) << 2;    // 0,4,8,12
  const int brow = tid >> 4;          // 0..15
  const int bng  = (tid & 15) << 2;   // 0..60

  for (int kt = 0; kt < K; kt += 16) {
    const float4 av = *(const float4*)(A  + (size_t)(m0 + arow) * K + kt + akg);
    const float4 bv = *(const float4*)(Bm + (size_t)(kt + brow) * N + n0 + bng);
    __syncthreads();
    As[akg + 0][arow] = av.x;
    As[akg + 1][arow] = av.y;
    As[akg + 2][arow] = av.z;
    As[akg + 3][arow] = av.w;
    *(float4*)(&Bs[brow][bng]) = bv;
    __syncthreads();
#pragma unroll
    for (int kk = 0; kk < 16; ++kk) {
      const float4 a = *(const float4*)(&As[kk][ty << 2]);
      const float4 b = *(const float4*)(&Bs[kk][tx << 2]);
      const float ap[4] = {a.x, a.y, a.z, a.w};
      const float bp[4] = {b.x, b.y, b.z, b.w};
#pragma unroll
      for (int p = 0; p < 4; ++p)
#pragma unroll
        for (int q = 0; q < 4; ++q)
          acc[p][q] = fmaf(ap[p], bp[q], acc[p][q]);
    }
  }
}

// ---------- kernel 1: rep = elu(x @ fc_w + fc_b) ----------
__global__ __launch_bounds__(256) void k_rep(const float* __restrict__ x,
    const float* __restrict__ fc_w, const float* __restrict__ fc_b,
    float* __restrict__ rep)
{
  __shared__ float As[16][68], Bs[16][68];
  float acc[4][4] = {};
  const int m0 = blockIdx.y * 64, n0 = blockIdx.x * 64;
  gemm64_acc(x, fc_w, DH, DH, m0, n0, acc, As, Bs);
  const int tx = threadIdx.x & 15, ty = threadIdx.x >> 4;
#pragma unroll
  for (int p = 0; p < 4; ++p) {
    const int m = m0 + (ty << 2) + p;
#pragma unroll
    for (int q = 0; q < 4; ++q) {
      const int n = n0 + (tx << 2) + q;
      const float v = acc[p][q] + fc_b[n];
      rep[(size_t)m * DH + n] = v > 0.0f ? v : (__expf(v) - 1.0f);
    }
  }
}

// ---------- kernel 2: dep = rep@w1+b1 ; head = rep@w2+b2 ; g1 = rep@wf1 ----------
__global__ __launch_bounds__(256) void k_triple(const float* __restrict__ rep,
    const float* __restrict__ w1, const float* __restrict__ b1,
    const float* __restrict__ w2, const float* __restrict__ b2,
    const float* __restrict__ wf1,
    float* __restrict__ dep, float* __restrict__ head, float* __restrict__ g1)
{
  __shared__ float As[16][68], Bs[16][68];
  const float* Bm; const float* bias; float* outp;
  if      (blockIdx.z == 0) { Bm = w1;  bias = b1;      outp = dep;  }
  else if (blockIdx.z == 1) { Bm = w2;  bias = b2;      outp = head; }
  else                      { Bm = wf1; bias = nullptr; outp = g1;   }
  float acc[4][4] = {};
  const int m0 = blockIdx.y * 64, n0 = blockIdx.x * 64;
  gemm64_acc(rep, Bm, DH, DH, m0, n0, acc, As, Bs);
  const int tx = threadIdx.x & 15, ty = threadIdx.x >> 4;
#pragma unroll
  for (int p = 0; p < 4; ++p) {
    const int m = m0 + (ty << 2) + p;
#pragma unroll
    for (int q = 0; q < 4; ++q) {
      const int n = n0 + (tx << 2) + q;
      float v = acc[p][q];
      if (bias) v += bias[n];
      outp[(size_t)m * DH + n] = v;
    }
  }
}

// ---------- kernel 3a: phase-1 chunked masked tanh-clip softmax partials ----------
// For j-chunk c: psa[b][i][c][h] = sum_{j in chunk, allowed} w ; paa = sum w*rep
// w = exp(C*tanh((dep[b,j,h]+head[b,i,h]+bl[h])/C)) for j>i ; row L-1 fully masked -> w=1 (uniform)
__global__ __launch_bounds__(512) void k_attn1(const float* __restrict__ dep,
    const float* __restrict__ head, const float* __restrict__ rep,
    const float* __restrict__ b_logit,
    float* __restrict__ psa, float* __restrict__ paa)
{
  const int h  = threadIdx.x;
  const int b  = blockIdx.z;
  const int c  = blockIdx.y;
  const int i0 = blockIdx.x * TI2;
  const int j0 = c * CH;
  const bool tail = (i0 + TI2 == L);       // contains fully-masked row L-1

  float sa[TI2] = {}, aa[TI2] = {};
  int jj0 = tail ? 0 : (i0 + 1 - j0);
  if (jj0 < 0) jj0 = 0;
  if (jj0 < CH) {
    float hb[TI2];
#pragma unroll
    for (int r = 0; r < TI2; ++r)
      hb[r] = head[((size_t)b * L + i0 + r) * DH + h] + b_logit[h];
    const float* dp = dep + ((size_t)b * L + j0) * DH + h;
    const float* rp = rep + ((size_t)b * L + j0) * DH + h;
    const float invs = 2.0f / CCLIP;
    const float twoC = 2.0f * CCLIP;
    for (int jj = jj0; jj < CH; ++jj) {
      const int j = j0 + jj;
      const float d  = dp[(size_t)jj * DH];
      const float rv = rp[(size_t)jj * DH];
#pragma unroll
      for (int r = 0; r < TI2; ++r) {
        const int i = i0 + r;
        const float u = (d + hb[r]) * invs;                 // 2*(dep+head+bl)/C
        const float e = __expf(u);
        const float t = CCLIP - twoC * __builtin_amdgcn_rcpf(e + 1.0f); // C*tanh(./C)
        float w = (j > i) ? __expf(t) : 0.0f;
        if (i == L - 1) w = 1.0f;                           // uniform row
        sa[r] += w;
        aa[r] = fmaf(w, rv, aa[r]);
      }
    }
  }
#pragma unroll
  for (int r = 0; r < TI2; ++r) {
    const size_t o = (((size_t)b * L + i0 + r) * NC + c) * DH + h;
    psa[o] = sa[r];
    paa[o] = aa[r];
  }
}

// ---------- kernel 3b: phase-2 reduce partials, normalize ----------
__global__ __launch_bounds__(256) void k_attn2(const float* __restrict__ psa,
    const float* __restrict__ paa, float* __restrict__ attn)
{
  const int t   = blockIdx.x * 256 + threadIdx.x;   // (b*L+i)*DH + h
  const int row = t >> 9;
  const int h   = t & (DH - 1);
  const size_t base = (size_t)row * NC * DH + h;
  float sa = 0.0f, aa = 0.0f;
#pragma unroll
  for (int c = 0; c < NC; ++c) {
    sa += psa[base + (size_t)c * DH];
    aa += paa[base + (size_t)c * DH];
  }
  attn[t] = aa * __builtin_amdgcn_rcpf(sa);
}

// ---------- kernel 4: g2 = attn@wf2 ; gate = sigmoid(g1+g2+bf) ; out = gate*rep+(1-gate)*attn ----------
__global__ __launch_bounds__(256) void k_final(const float* __restrict__ attn,
    const float* __restrict__ wf2, const float* __restrict__ g1,
    const float* __restrict__ rep, const float* __restrict__ bf,
    float* __restrict__ out)
{
  __shared__ float As[16][68], Bs[16][68];
  float acc[4][4] = {};
  const int m0 = blockIdx.y * 64, n0 = blockIdx.x * 64;
  gemm64_acc(attn, wf2, DH, DH, m0, n0, acc, As, Bs);
  const int tx = threadIdx.x & 15, ty = threadIdx.x >> 4;
#pragma unroll
  for (int p = 0; p < 4; ++p) {
    const int m = m0 + (ty << 2) + p;
#pragma unroll
    for (int q = 0; q < 4; ++q) {
      const int n = n0 + (tx << 2) + q;
      const size_t idx = (size_t)m * DH + n;
      const float s = g1[idx] + acc[p][q] + bf[n];
      const float gate = __builtin_amdgcn_rcpf(1.0f + __expf(-s));
      out[idx] = gate * rep[idx] + (1.0f - gate) * attn[idx];
    }
  }
}

extern "C" void kernel_launch(void* const* d_in, const int* in_sizes, int n_in,
                              void* d_out, int out_size, void* d_ws, size_t ws_size,
                              hipStream_t stream)
{
  const float* x       = (const float*)d_in[0];
  const float* fc_w    = (const float*)d_in[1];
  const float* fc_b    = (const float*)d_in[2];
  const float* w1_w    = (const float*)d_in[3];
  const float* w1_b    = (const float*)d_in[4];
  const float* w2_w    = (const float*)d_in[5];
  const float* w2_b    = (const float*)d_in[6];
  const float* b_logit = (const float*)d_in[7];
  const float* wf1_w   = (const float*)d_in[8];
  const float* wf2_w   = (const float*)d_in[9];
  const float* bf      = (const float*)d_in[10];
  float* out = (float*)d_out;

  const size_t MAT = (size_t)BQ * L * DH;          // 262144 floats
  float* ws   = (float*)d_ws;
  float* rep  = ws;
  float* dep  = ws + 1 * MAT;
  float* head = ws + 2 * MAT;
  float* g1   = ws + 3 * MAT;
  float* attn = ws + 4 * MAT;
  float* psa  = ws + 5 * MAT;                      // [B][L][NC][DH]
  float* paa  = ws + 5 * MAT + MAT * NC;

  const dim3 blk(256);
  k_rep   <<<dim3(8, 8),            blk,       0, stream>>>(x, fc_w, fc_b, rep);
  k_triple<<<dim3(8, 8, 3),         blk,       0, stream>>>(rep, w1_w, w1_b, w2_w, w2_b, wf1_w, dep, head, g1);
  k_attn1 <<<dim3(L / TI2, NC, BQ), dim3(512), 0, stream>>>(dep, head, rep, b_logit, psa, paa);
  k_attn2 <<<dim3((BQ * L * DH) / 256), blk,   0, stream>>>(psa, paa, attn);
  k_final <<<dim3(8, 8),            blk,       0, stream>>>(attn, wf2_w, g1, rep, bf, out);
}

// Round 3
// 67.308 us; speedup vs baseline: 2.0369x; 1.9059x over previous
//
#include <hip/hip_runtime.h>
#include <hip/hip_bf16.h>

#define L 256
#define DH 512
#define BQ 2
#define MT 512            // total rows = BQ*L
#define CCLIP 5.0f
#define NC 4              // j-chunks for two-phase softmax
#define CH (L / NC)
#define TI2 2

typedef __attribute__((ext_vector_type(8))) short bf16x8;
typedef __attribute__((ext_vector_type(4))) float f32x4;

static __device__ __forceinline__ ushort f2b(float v) {
  __hip_bfloat16 h = __float2bfloat16(v);
  return *reinterpret_cast<ushort*>(&h);
}

// ---------- conversion: z=0..4 transpose+cast weights to [N][K] bf16; z=5 cast x ----------
__global__ __launch_bounds__(256) void k_conv(
    const float* __restrict__ x,
    const float* __restrict__ fcw, const float* __restrict__ w1,
    const float* __restrict__ w2, const float* __restrict__ wf1,
    const float* __restrict__ wf2,
    ushort* __restrict__ xb,
    ushort* __restrict__ fcwt, ushort* __restrict__ w1t,
    ushort* __restrict__ w2t, ushort* __restrict__ wf1t,
    ushort* __restrict__ wf2t)
{
  const int z = blockIdx.z;
  const float* src; ushort* dst;
  switch (z) {
    case 0: src = fcw; dst = fcwt; break;
    case 1: src = w1;  dst = w1t;  break;
    case 2: src = w2;  dst = w2t;  break;
    case 3: src = wf1; dst = wf1t; break;
    case 4: src = wf2; dst = wf2t; break;
    default: src = x;  dst = xb;   break;
  }
  const int tx = threadIdx.x & 31, ty = threadIdx.x >> 5;
  const int c0 = blockIdx.x * 32, r0 = blockIdx.y * 32;
  if (z == 5) {
#pragma unroll
    for (int r = 0; r < 4; ++r) {
      const int row = r0 + ty + 8 * r;
      dst[(size_t)row * 512 + c0 + tx] = f2b(src[(size_t)row * 512 + c0 + tx]);
    }
  } else {
    __shared__ float t[32][33];
#pragma unroll
    for (int r = 0; r < 4; ++r)
      t[ty + 8 * r][tx] = src[(size_t)(r0 + ty + 8 * r) * 512 + c0 + tx];
    __syncthreads();
#pragma unroll
    for (int r = 0; r < 4; ++r)
      dst[(size_t)(c0 + ty + 8 * r) * 512 + r0 + tx] = f2b(t[tx][ty + 8 * r]);
  }
}

// ---------- 1-wave 32x32 MFMA tile: A [M][512] bf16 row-major, Bt [N][512] bf16 ----------
__device__ __forceinline__ void mfma32(const ushort* __restrict__ A,
                                       const ushort* __restrict__ Bt,
                                       int m0, int n0, f32x4 (&acc)[2][2])
{
  const int l  = threadIdx.x & 63;
  const int fr = l & 15;
  const int kg = (l >> 4) << 3;     // 0,8,16,24
  const ushort* pa0 = A  + (size_t)(m0 + fr) * DH + kg;
  const ushort* pa1 = pa0 + 16 * DH;
  const ushort* pb0 = Bt + (size_t)(n0 + fr) * DH + kg;
  const ushort* pb1 = pb0 + 16 * DH;
#pragma unroll 4
  for (int kt = 0; kt < DH; kt += 32) {
    const bf16x8 a0 = *(const bf16x8*)(pa0 + kt);
    const bf16x8 a1 = *(const bf16x8*)(pa1 + kt);
    const bf16x8 b0 = *(const bf16x8*)(pb0 + kt);
    const bf16x8 b1 = *(const bf16x8*)(pb1 + kt);
    acc[0][0] = __builtin_amdgcn_mfma_f32_16x16x32_bf16(a0, b0, acc[0][0], 0, 0, 0);
    acc[0][1] = __builtin_amdgcn_mfma_f32_16x16x32_bf16(a0, b1, acc[0][1], 0, 0, 0);
    acc[1][0] = __builtin_amdgcn_mfma_f32_16x16x32_bf16(a1, b0, acc[1][0], 0, 0, 0);
    acc[1][1] = __builtin_amdgcn_mfma_f32_16x16x32_bf16(a1, b1, acc[1][1], 0, 0, 0);
  }
}

// ---------- kernel: rep = elu(x@fc_w + b) ; writes fp32 + bf16 ----------
__global__ __launch_bounds__(64) void k_rep_g(const ushort* __restrict__ xb,
    const ushort* __restrict__ fcwt, const float* __restrict__ fcb,
    float* __restrict__ rep, ushort* __restrict__ repb)
{
  f32x4 acc[2][2] = {};
  const int m0 = blockIdx.y * 32, n0 = blockIdx.x * 32;
  mfma32(xb, fcwt, m0, n0, acc);
  const int l = threadIdx.x & 63;
  const int fr = l & 15, rg = (l >> 4) << 2;
#pragma unroll
  for (int mi = 0; mi < 2; ++mi)
#pragma unroll
    for (int ni = 0; ni < 2; ++ni) {
      const int col = n0 + ni * 16 + fr;
      const int row = m0 + mi * 16 + rg;
      const float bv = fcb[col];
#pragma unroll
      for (int r = 0; r < 4; ++r) {
        float v = acc[mi][ni][r] + bv;
        v = v > 0.0f ? v : (__expf(v) - 1.0f);
        const size_t idx = (size_t)(row + r) * DH + col;
        rep[idx] = v;
        repb[idx] = f2b(v);
      }
    }
}

// ---------- kernel: dep = rep@w1+b1 ; head = rep@w2+b2 ; g1 = rep@wf1 ----------
__global__ __launch_bounds__(64) void k_triple_g(const ushort* __restrict__ repb,
    const ushort* __restrict__ w1t, const float* __restrict__ b1,
    const ushort* __restrict__ w2t, const float* __restrict__ b2,
    const ushort* __restrict__ wf1t,
    float* __restrict__ dep, float* __restrict__ head, float* __restrict__ g1)
{
  const ushort* Bt; const float* bias; float* outp;
  if      (blockIdx.z == 0) { Bt = w1t;  bias = b1;      outp = dep;  }
  else if (blockIdx.z == 1) { Bt = w2t;  bias = b2;      outp = head; }
  else                      { Bt = wf1t; bias = nullptr; outp = g1;   }
  f32x4 acc[2][2] = {};
  const int m0 = blockIdx.y * 32, n0 = blockIdx.x * 32;
  mfma32(repb, Bt, m0, n0, acc);
  const int l = threadIdx.x & 63;
  const int fr = l & 15, rg = (l >> 4) << 2;
#pragma unroll
  for (int mi = 0; mi < 2; ++mi)
#pragma unroll
    for (int ni = 0; ni < 2; ++ni) {
      const int col = n0 + ni * 16 + fr;
      const int row = m0 + mi * 16 + rg;
      const float bv = bias ? bias[col] : 0.0f;
#pragma unroll
      for (int r = 0; r < 4; ++r)
        outp[(size_t)(row + r) * DH + col] = acc[mi][ni][r] + bv;
    }
}

// ---------- phase-1 chunked masked tanh-clip softmax partials ----------
__global__ __launch_bounds__(512) void k_attn1(const float* __restrict__ dep,
    const float* __restrict__ head, const float* __restrict__ rep,
    const float* __restrict__ b_logit,
    float* __restrict__ psa, float* __restrict__ paa)
{
  const int h  = threadIdx.x;
  const int b  = blockIdx.z;
  const int c  = blockIdx.y;
  const int i0 = blockIdx.x * TI2;
  const int j0 = c * CH;
  const bool tail = (i0 + TI2 == L);       // contains fully-masked row L-1

  float sa[TI2] = {}, aa[TI2] = {};
  int jj0 = tail ? 0 : (i0 + 1 - j0);
  if (jj0 < 0) jj0 = 0;
  if (jj0 < CH) {
    float hb[TI2];
#pragma unroll
    for (int r = 0; r < TI2; ++r)
      hb[r] = head[((size_t)b * L + i0 + r) * DH + h] + b_logit[h];
    const float* dp = dep + ((size_t)b * L + j0) * DH + h;
    const float* rp = rep + ((size_t)b * L + j0) * DH + h;
    const float invs = 2.0f / CCLIP;
    const float twoC = 2.0f * CCLIP;
    for (int jj = jj0; jj < CH; ++jj) {
      const int j = j0 + jj;
      const float d  = dp[(size_t)jj * DH];
      const float rv = rp[(size_t)jj * DH];
#pragma unroll
      for (int r = 0; r < TI2; ++r) {
        const int i = i0 + r;
        const float u = (d + hb[r]) * invs;
        const float e = __expf(u);
        const float t = CCLIP - twoC * __builtin_amdgcn_rcpf(e + 1.0f); // C*tanh(./C)
        float w = (j > i) ? __expf(t) : 0.0f;
        if (i == L - 1) w = 1.0f;            // fully-masked row -> uniform
        sa[r] += w;
        aa[r] = fmaf(w, rv, aa[r]);
      }
    }
  }
#pragma unroll
  for (int r = 0; r < TI2; ++r) {
    const size_t o = (((size_t)b * L + i0 + r) * NC + c) * DH + h;
    psa[o] = sa[r];
    paa[o] = aa[r];
  }
}

// ---------- phase-2 reduce partials, normalize; fp32 + bf16 ----------
__global__ __launch_bounds__(256) void k_attn2(const float* __restrict__ psa,
    const float* __restrict__ paa, float* __restrict__ attn,
    ushort* __restrict__ attnb)
{
  const int t   = blockIdx.x * 256 + threadIdx.x;
  const int row = t >> 9;
  const int h   = t & (DH - 1);
  const size_t base = (size_t)row * NC * DH + h;
  float sa = 0.0f, aa = 0.0f;
#pragma unroll
  for (int c = 0; c < NC; ++c) {
    sa += psa[base + (size_t)c * DH];
    aa += paa[base + (size_t)c * DH];
  }
  const float v = aa * __builtin_amdgcn_rcpf(sa);
  attn[t] = v;
  attnb[t] = f2b(v);
}

// ---------- final: g2 = attn@wf2 ; gate = sigmoid(g1+g2+bf) ; mix ----------
__global__ __launch_bounds__(64) void k_final_g(const ushort* __restrict__ attnb,
    const ushort* __restrict__ wf2t, const float* __restrict__ g1,
    const float* __restrict__ rep, const float* __restrict__ attn,
    const float* __restrict__ bf, float* __restrict__ out)
{
  f32x4 acc[2][2] = {};
  const int m0 = blockIdx.y * 32, n0 = blockIdx.x * 32;
  mfma32(attnb, wf2t, m0, n0, acc);
  const int l = threadIdx.x & 63;
  const int fr = l & 15, rg = (l >> 4) << 2;
#pragma unroll
  for (int mi = 0; mi < 2; ++mi)
#pragma unroll
    for (int ni = 0; ni < 2; ++ni) {
      const int col = n0 + ni * 16 + fr;
      const int row = m0 + mi * 16 + rg;
      const float bv = bf[col];
#pragma unroll
      for (int r = 0; r < 4; ++r) {
        const size_t idx = (size_t)(row + r) * DH + col;
        const float s = g1[idx] + acc[mi][ni][r] + bv;
        const float gate = __builtin_amdgcn_rcpf(1.0f + __expf(-s));
        out[idx] = gate * rep[idx] + (1.0f - gate) * attn[idx];
      }
    }
}

extern "C" void kernel_launch(void* const* d_in, const int* in_sizes, int n_in,
                              void* d_out, int out_size, void* d_ws, size_t ws_size,
                              hipStream_t stream)
{
  const float* x       = (const float*)d_in[0];
  const float* fc_w    = (const float*)d_in[1];
  const float* fc_b    = (const float*)d_in[2];
  const float* w1_w    = (const float*)d_in[3];
  const float* w1_b    = (const float*)d_in[4];
  const float* w2_w    = (const float*)d_in[5];
  const float* w2_b    = (const float*)d_in[6];
  const float* b_logit = (const float*)d_in[7];
  const float* wf1_w   = (const float*)d_in[8];
  const float* wf2_w   = (const float*)d_in[9];
  const float* bf      = (const float*)d_in[10];
  float* out = (float*)d_out;

  const size_t MAT = (size_t)MT * DH;              // 262144
  float* ws    = (float*)d_ws;
  float* rep   = ws;
  float* dep   = ws + 1 * MAT;
  float* head  = ws + 2 * MAT;
  float* g1    = ws + 3 * MAT;
  float* attn  = ws + 4 * MAT;
  float* psa   = ws + 5 * MAT;                     // [B][L][NC][DH] = 4*MAT
  float* paa   = ws + 9 * MAT;                     // 4*MAT
  ushort* ub   = (ushort*)(ws + 13 * MAT);
  ushort* xb    = ub + 0 * MAT;
  ushort* repb  = ub + 1 * MAT;
  ushort* attnb = ub + 2 * MAT;
  ushort* fcwt  = ub + 3 * MAT;
  ushort* w1t   = ub + 4 * MAT;
  ushort* w2t   = ub + 5 * MAT;
  ushort* wf1t  = ub + 6 * MAT;
  ushort* wf2t  = ub + 7 * MAT;

  k_conv   <<<dim3(16, 16, 6), dim3(256), 0, stream>>>(x, fc_w, w1_w, w2_w, wf1_w, wf2_w,
                                                       xb, fcwt, w1t, w2t, wf1t, wf2t);
  k_rep_g  <<<dim3(16, 16),    dim3(64),  0, stream>>>(xb, fcwt, fc_b, rep, repb);
  k_triple_g<<<dim3(16, 16, 3), dim3(64), 0, stream>>>(repb, w1t, w1_b, w2t, w2_b, wf1t,
                                                       dep, head, g1);
  k_attn1  <<<dim3(L / TI2, NC, BQ), dim3(512), 0, stream>>>(dep, head, rep, b_logit, psa, paa);
  k_attn2  <<<dim3((BQ * L * DH) / 256), dim3(256), 0, stream>>>(psa, paa, attn, attnb);
  k_final_g<<<dim3(16, 16),    dim3(64),  0, stream>>>(attnb, wf2t, g1, rep, attn, bf, out);
}